// Round 2
// baseline (1035.381 us; speedup 1.0000x reference)
//
#include <hip/hip_runtime.h>

#define BATCH 32
#define NCAPS 32
#define NR    4608
#define NI    8
#define NO    16
#define CSTR  200   // floats per capsule row in LDS: o*12 layout + pad; 800B, 16B-aligned reads

// Routing pass: per route node r, u[c] = x[b,r,:] . W[c,r,:,o]; softmax over c of
// (u[c]*A[b,c,o]); accumulate sum_r softmax*u into per-chunk partials.
// Lane layout: b = t&31 (lane-major) so a wave = 32 b x 2 o -> LDS reads are
// 8-distinct-word broadcasts (conflict-free, minimal LDS pipe time).
__global__ __launch_bounds__(512, 2) void caps_route_pass(
    const float* __restrict__ x,    // [B][R][I]
    const float* __restrict__ W,    // [C][R][I][O]
    const float* __restrict__ A,    // [B][C][O]
    float* __restrict__ P,          // [nchunk][B][C][O]
    int rb)
{
    __shared__ float Ws[2][NCAPS * CSTR];   // 2 x 25.6 KB

    const int t = threadIdx.x;
    const int b = t & 31;
    const int o = (t >> 5) & 15;
    const int r0 = blockIdx.x * rb;

    float a[NCAPS];
#pragma unroll
    for (int c = 0; c < NCAPS; ++c) a[c] = A[(b * NCAPS + c) * NO + o];

    float acc[NCAPS];
#pragma unroll
    for (int c = 0; c < NCAPS; ++c) acc[c] = 0.f;

    // Staging role: 4 consecutive capsules x 16 segments per wave -> coalesced
    // global loads (4 x 512B) and conflict-free LDS writes (32 banks, 2-way max).
    const int cs  = t >> 4;          // capsule to stage (0..31)
    const int seg = t & 15;          // 8-float segment of the 128-float (i,o) block
    const int iw  = seg >> 1;
    const int ob  = (seg & 1) * 8;
    const float* wsrc = W + ((size_t)cs * NR + r0) * (NI * NO) + seg * 8;
    const float* xp   = x + ((size_t)b * NR + r0) * NI;

    // Prologue: stage r0, prefetch r1 (W and x) into registers.
    {
        const float4 s0 = *(const float4*)(wsrc);
        const float4 s1 = *(const float4*)(wsrc + 4);
        const float tmp[8] = {s0.x, s0.y, s0.z, s0.w, s1.x, s1.y, s1.z, s1.w};
#pragma unroll
        for (int k = 0; k < 8; ++k)
            Ws[0][cs * CSTR + (ob + k) * 12 + iw] = tmp[k];
    }
    float4 xc0 = *(const float4*)(xp);
    float4 xc1 = *(const float4*)(xp + 4);
    float4 pw0, pw1, xn0, xn1;
    if (rb > 1) {
        pw0 = *(const float4*)(wsrc + NI * NO);
        pw1 = *(const float4*)(wsrc + NI * NO + 4);
        xn0 = *(const float4*)(xp + NI);
        xn1 = *(const float4*)(xp + NI + 4);
    }
    __syncthreads();

    for (int rr = 0; rr < rb; ++rr) {
        const int cur = rr & 1;

        // ---- compute r = r0+rr from Ws[cur] ----
        float u[NCAPS], e[NCAPS];
        float m = -3.0e38f;
        const float* bp = &Ws[cur][o * 12];
#pragma unroll
        for (int c = 0; c < NCAPS; ++c) {
            const float* wp = bp + c * CSTR;
            const float4 w0 = *(const float4*)(wp);
            const float4 w1 = *(const float4*)(wp + 4);
            float uu =      xc0.x * w0.x;
            uu = fmaf(xc0.y, w0.y, uu);
            uu = fmaf(xc0.z, w0.z, uu);
            uu = fmaf(xc0.w, w0.w, uu);
            uu = fmaf(xc1.x, w1.x, uu);
            uu = fmaf(xc1.y, w1.y, uu);
            uu = fmaf(xc1.z, w1.z, uu);
            uu = fmaf(xc1.w, w1.w, uu);
            u[c] = uu;
            const float l = uu * a[c];
            e[c] = l;
            m = fmaxf(m, l);
        }
        float Z = 0.f;
#pragma unroll
        for (int c = 0; c < NCAPS; ++c) {
            const float ee = __expf(e[c] - m);
            e[c] = ee;
            Z += ee;
        }
        const float rz = 1.0f / Z;
#pragma unroll
        for (int c = 0; c < NCAPS; ++c)
            acc[c] = fmaf(e[c] * rz, u[c], acc[c]);

        // ---- stage r+1 into the other buffer; prefetch r+2 ----
        if (rr + 1 < rb) {
            const float tmp[8] = {pw0.x, pw0.y, pw0.z, pw0.w,
                                  pw1.x, pw1.y, pw1.z, pw1.w};
#pragma unroll
            for (int k = 0; k < 8; ++k)
                Ws[cur ^ 1][cs * CSTR + (ob + k) * 12 + iw] = tmp[k];
            xc0 = xn0; xc1 = xn1;
            if (rr + 2 < rb) {
                const float* wn = wsrc + (size_t)(rr + 2) * (NI * NO);
                pw0 = *(const float4*)(wn);
                pw1 = *(const float4*)(wn + 4);
                const float* xn = xp + (size_t)(rr + 2) * NI;
                xn0 = *(const float4*)(xn);
                xn1 = *(const float4*)(xn + 4);
            }
        }
        __syncthreads();
    }

    float* pout = P + (((size_t)blockIdx.x * BATCH + b) * NCAPS) * NO + o;
#pragma unroll
    for (int c = 0; c < NCAPS; ++c) pout[c * NO] = acc[c];
}

// Reduce partials over chunks, squash, update A; emit V on the final iteration.
__global__ void caps_reduce_squash(const float* __restrict__ P,
                                   float* __restrict__ A,
                                   float* __restrict__ out,
                                   int nchunk)
{
    __shared__ float sm[256];
    const int bc  = blockIdx.x;     // b*NCAPS + c
    const int tid = threadIdx.x;    // 256 = 16 j x 16 o
    const int o = tid & 15;
    const int j = tid >> 4;
    float s = 0.f;
    for (int t = j; t < nchunk; t += 16)
        s += P[((size_t)t * (BATCH * NCAPS) + bc) * NO + o];
    sm[tid] = s;
    __syncthreads();
    if (tid < 16) {
        float S = 0.f;
#pragma unroll
        for (int k = 0; k < 16; ++k) S += sm[tid + 16 * k];
        float sq = S * S;
#pragma unroll
        for (int d = 8; d >= 1; d >>= 1) sq += __shfl_xor(sq, d, 16);
        const float scale = sq / ((1.f + sq) * sqrtf(sq));
        const float V = S * scale;
        const int idx = bc * NO + tid;
        A[idx] += V;
        if (out) out[idx] = V;
    }
}

__global__ void caps_zero(float* __restrict__ p, int n)
{
    const int i = blockIdx.x * blockDim.x + threadIdx.x;
    if (i < n) p[i] = 0.f;
}

extern "C" void kernel_launch(void* const* d_in, const int* in_sizes, int n_in,
                              void* d_out, int out_size, void* d_ws, size_t ws_size,
                              hipStream_t stream)
{
    const float* x = (const float*)d_in[0];   // [32][4608][8]
    const float* W = (const float*)d_in[1];   // [32][4608][8][16]
    float* out = (float*)d_out;               // [32][32][16]

    float* A = (float*)d_ws;                        // 16384 floats
    float* P = A + BATCH * NCAPS * NO;

    // Largest power-of-two chunk count whose partial buffer fits the workspace.
    // 512 -> rb=9 -> grid 512 = 2 blocks/CU (16 waves/CU).
    int nchunk = 512;
    while (nchunk > 1 &&
           (size_t)(nchunk + 1) * (BATCH * NCAPS * NO) * sizeof(float) > ws_size)
        nchunk >>= 1;
    const int rb = NR / nchunk;

    caps_zero<<<(BATCH * NCAPS * NO + 255) / 256, 256, 0, stream>>>(A, BATCH * NCAPS * NO);

    for (int it = 0; it < 3; ++it) {
        caps_route_pass<<<nchunk, 512, 0, stream>>>(x, W, A, P, rb);
        caps_reduce_squash<<<BATCH * NCAPS, 256, 0, stream>>>(
            P, A, it == 2 ? out : nullptr, nchunk);
    }
}

// Round 3
// 800.713 us; speedup vs baseline: 1.2931x; 1.2931x over previous
//
#include <hip/hip_runtime.h>

#define BATCH 32
#define NCAPS 32
#define NR    4608
#define NI    8
#define NO    16
#define CSTR  200   // LDS floats per capsule: o*12 layout + pad (write banks 2-way max)
#define MAXRB 36    // xs sized for nchunk down to 128

// Routing pass: per route node r, u[c] = x[b,r,:] . W[c,r,:,o]; softmax over c of
// (u[c]*A[b,c,o]); accumulate sum_r softmax*u into per-chunk partials.
// Lane layout o-major: wave = 32 b x 2 o -> W LDS reads are 2-address broadcasts.
__global__ __launch_bounds__(512, 4) void caps_route_pass(
    const float* __restrict__ x,    // [B][R][I]
    const float* __restrict__ W,    // [C][R][I][O]
    const float* __restrict__ A,    // [B][C][O]
    float* __restrict__ P,          // [nchunk][B][C][O]
    int rb)
{
    __shared__ float Ws[NCAPS * CSTR];          // 25.6 KB
    __shared__ float xs[MAXRB * BATCH * NI];    // 36.9 KB (rb*1KB used)

    const int t = threadIdx.x;
    const int b = t & 31;
    const int o = t >> 5;          // 0..15
    const int r0 = blockIdx.x * rb;

    float a[NCAPS];
#pragma unroll
    for (int c = 0; c < NCAPS; ++c) a[c] = A[(b * NCAPS + c) * NO + o];

    float acc[NCAPS];
#pragma unroll
    for (int c = 0; c < NCAPS; ++c) acc[c] = 0.f;

    // Stage x[:, r0..r0+rb, :] into LDS once (tiny: rb KB).
    for (int idx = t; idx < rb * BATCH * NI; idx += 512) {
        const int rr  = idx >> 8;        // BATCH*NI = 256
        const int rem = idx & 255;
        const int bb  = rem >> 3;
        const int ii  = rem & 7;
        xs[idx] = x[((size_t)bb * NR + r0 + rr) * NI + ii];
    }

    // W staging role: 4 consecutive capsules x 16 segments per wave -> coalesced
    // global loads; LDS writes 2-way bank aliased (free).
    const int cs  = t >> 4;          // capsule to stage
    const int seg = t & 15;          // 8-float segment of the 128-float (i,o) block
    const int iw  = seg >> 1;
    const int ob  = (seg & 1) * 8;
    const float* wsrc = W + ((size_t)cs * NR + r0) * (NI * NO) + seg * 8;

    // 1-deep register prefetch of W (round-1 proven footprint: no spills).
    float4 pf0 = *(const float4*)(wsrc);
    float4 pf1 = *(const float4*)(wsrc + 4);

    for (int rr = 0; rr < rb; ++rr) {
        __syncthreads();   // previous iteration's readers done (iter 0: xs staged)
        {
            const float tmp[8] = {pf0.x, pf0.y, pf0.z, pf0.w,
                                  pf1.x, pf1.y, pf1.z, pf1.w};
#pragma unroll
            for (int k = 0; k < 8; ++k)
                Ws[cs * CSTR + (ob + k) * 12 + iw] = tmp[k];
        }
        if (rr + 1 < rb) {
            wsrc += NI * NO;
            pf0 = *(const float4*)(wsrc);
            pf1 = *(const float4*)(wsrc + 4);
        }
        __syncthreads();

        const float4 xc0 = *(const float4*)(&xs[rr * 256 + b * 8]);
        const float4 xc1 = *(const float4*)(&xs[rr * 256 + b * 8 + 4]);

        float u[NCAPS], e[NCAPS];
        const float* bp = &Ws[o * 12];
#pragma unroll
        for (int c = 0; c < NCAPS; ++c) {
            const float* wp = bp + c * CSTR;
            const float4 w0 = *(const float4*)(wp);
            const float4 w1 = *(const float4*)(wp + 4);
            float uu =      xc0.x * w0.x;
            uu = fmaf(xc0.y, w0.y, uu);
            uu = fmaf(xc0.z, w0.z, uu);
            uu = fmaf(xc0.w, w0.w, uu);
            uu = fmaf(xc1.x, w1.x, uu);
            uu = fmaf(xc1.y, w1.y, uu);
            uu = fmaf(xc1.z, w1.z, uu);
            uu = fmaf(xc1.w, w1.w, uu);
            u[c] = uu;
        }
        // Softmax without max-subtraction: |u*a| < ~50 -> exp safely in range.
        float Z = 0.f;
#pragma unroll
        for (int c = 0; c < NCAPS; ++c) {
            const float ee = __expf(u[c] * a[c]);
            e[c] = ee;
            Z += ee;
        }
        const float rz = 1.0f / Z;
#pragma unroll
        for (int c = 0; c < NCAPS; ++c)
            acc[c] = fmaf(e[c] * rz, u[c], acc[c]);
    }

    float* pout = P + (((size_t)blockIdx.x * BATCH + b) * NCAPS) * NO + o;
#pragma unroll
    for (int c = 0; c < NCAPS; ++c) pout[c * NO] = acc[c];
}

// Reduce partials over chunks, squash, update A; emit V on the final iteration.
__global__ void caps_reduce_squash(const float* __restrict__ P,
                                   float* __restrict__ A,
                                   float* __restrict__ out,
                                   int nchunk)
{
    __shared__ float sm[256];
    const int bc  = blockIdx.x;     // b*NCAPS + c
    const int tid = threadIdx.x;    // 256 = 16 j x 16 o
    const int o = tid & 15;
    const int j = tid >> 4;
    float s = 0.f;
    for (int t = j; t < nchunk; t += 16)
        s += P[((size_t)t * (BATCH * NCAPS) + bc) * NO + o];
    sm[tid] = s;
    __syncthreads();
    if (tid < 16) {
        float S = 0.f;
#pragma unroll
        for (int k = 0; k < 16; ++k) S += sm[tid + 16 * k];
        float sq = S * S;
#pragma unroll
        for (int d = 8; d >= 1; d >>= 1) sq += __shfl_xor(sq, d, 16);
        const float scale = sq / ((1.f + sq) * sqrtf(sq));
        const float V = S * scale;
        const int idx = bc * NO + tid;
        A[idx] += V;
        if (out) out[idx] = V;
    }
}

__global__ void caps_zero(float* __restrict__ p, int n)
{
    const int i = blockIdx.x * blockDim.x + threadIdx.x;
    if (i < n) p[i] = 0.f;
}

extern "C" void kernel_launch(void* const* d_in, const int* in_sizes, int n_in,
                              void* d_out, int out_size, void* d_ws, size_t ws_size,
                              hipStream_t stream)
{
    const float* x = (const float*)d_in[0];   // [32][4608][8]
    const float* W = (const float*)d_in[1];   // [32][4608][8][16]
    float* out = (float*)d_out;               // [32][32][16]

    float* A = (float*)d_ws;                        // 16384 floats
    float* P = A + BATCH * NCAPS * NO;

    // Largest power-of-two chunk count whose partial buffer fits the workspace.
    // 512 -> rb=9, grid 512 = 2 blocks/CU.
    int nchunk = 512;
    while (nchunk > 128 &&
           (size_t)(nchunk + 1) * (BATCH * NCAPS * NO) * sizeof(float) > ws_size)
        nchunk >>= 1;
    const int rb = NR / nchunk;

    caps_zero<<<(BATCH * NCAPS * NO + 255) / 256, 256, 0, stream>>>(A, BATCH * NCAPS * NO);

    for (int it = 0; it < 3; ++it) {
        caps_route_pass<<<nchunk, 512, 0, stream>>>(x, W, A, P, rb);
        caps_reduce_squash<<<BATCH * NCAPS, 256, 0, stream>>>(
            P, A, it == 2 ? out : nullptr, nchunk);
    }
}

// Round 4
// 362.309 us; speedup vs baseline: 2.8577x; 2.2100x over previous
//
#include <hip/hip_runtime.h>

#define BATCH 32
#define NCAPS 32
#define NR    4608
#define NI    8
#define NO    16
#define CSTR  200   // LDS floats per capsule row: o*12 layout + pad (writes 2-way max, reads 1-sweep)
#define MAXRB 36    // supports nchunk down to 128

// Routing pass: per route node r, u[c] = x[b,r,:] . W[c,r,:,o]; softmax over c of
// (u[c]*A[b,c,o]); accumulate sum_r softmax*u into per-chunk partials.
// Lane layout o-major: wave = 32 b x 2 o -> W LDS reads are 2-address broadcasts
// (~1 bank sweep per ds_read_b128), x LDS reads are 32-consecutive-word b32 reads.
__global__ __launch_bounds__(512, 2) void caps_route_pass(
    const float* __restrict__ x,    // [B][R][I]
    const float* __restrict__ W,    // [C][R][I][O]
    const float* __restrict__ A,    // [B][C][O]
    float* __restrict__ P,          // [nchunk][B][C][O]
    int rb)
{
    __shared__ __align__(16) float Ws[NCAPS * CSTR];       // 25.6 KB
    __shared__ __align__(16) float xsT[NI * MAXRB * BATCH]; // 36.9 KB ([i][rr][b], rb rows used)

    const int t = threadIdx.x;
    const int b = t & 31;
    const int o = t >> 5;          // 0..15
    const int r0 = blockIdx.x * rb;
    const int rbs = rb * BATCH;    // i-stride in xsT

    // Routing coefficients for this (b,o), pre-scaled by log2(e) so softmax uses exp2.
    float a2[NCAPS];
#pragma unroll
    for (int c = 0; c < NCAPS; ++c)
        a2[c] = A[(b * NCAPS + c) * NO + o] * 1.44269504088896341f;

    float acc[NCAPS];
#pragma unroll
    for (int c = 0; c < NCAPS; ++c) acc[c] = 0.f;

    // Stage x[:, r0..r0+rb, :] transposed into LDS once (conflict-free LDS writes).
    for (int s = t; s < rbs; s += 512) {
        const int rr = s >> 5;
        const int bb = s & 31;
        const float4 v0 = *(const float4*)&x[((size_t)bb * NR + r0 + rr) * NI];
        const float4 v1 = *(const float4*)&x[((size_t)bb * NR + r0 + rr) * NI + 4];
        const float tmp[8] = {v0.x, v0.y, v0.z, v0.w, v1.x, v1.y, v1.z, v1.w};
#pragma unroll
        for (int i = 0; i < NI; ++i)
            xsT[i * rbs + rr * BATCH + bb] = tmp[i];
    }

    // W staging role: 4 consecutive capsules x 16 segments per wave -> coalesced
    // global loads; LDS writes 2-way bank aliased (free).
    const int cs  = t >> 4;          // capsule to stage
    const int seg = t & 15;          // 8-float segment of the 128-float (i,o) block
    const int iw  = seg >> 1;
    const int ob  = (seg & 1) * 8;
    const float* wsrc = W + ((size_t)cs * NR + r0) * (NI * NO) + seg * 8;

    // 1-deep register prefetch of W (round-1 proven footprint: no spills).
    float4 pf0 = *(const float4*)(wsrc);
    float4 pf1 = *(const float4*)(wsrc + 4);

    for (int rr = 0; rr < rb; ++rr) {
        __syncthreads();   // previous iteration's readers done (iter 0: xsT staged)
        {
            const float tmp[8] = {pf0.x, pf0.y, pf0.z, pf0.w,
                                  pf1.x, pf1.y, pf1.z, pf1.w};
#pragma unroll
            for (int k = 0; k < 8; ++k)
                Ws[cs * CSTR + (ob + k) * 12 + iw] = tmp[k];
        }
        if (rr + 1 < rb) {
            wsrc += NI * NO;
            pf0 = *(const float4*)(wsrc);
            pf1 = *(const float4*)(wsrc + 4);
        }
        __syncthreads();

        // x[b, r0+rr, :] — 8 conflict-free broadcast LDS reads.
        const float* xrow = &xsT[rr * BATCH + b];
        float xq[NI];
#pragma unroll
        for (int i = 0; i < NI; ++i) xq[i] = xrow[i * rbs];

        float u[NCAPS], e[NCAPS];
        const float* bp = &Ws[o * 12];
#pragma unroll
        for (int c = 0; c < NCAPS; ++c) {
            const float* wp = bp + c * CSTR;
            const float4 w0 = *(const float4*)(wp);
            const float4 w1 = *(const float4*)(wp + 4);
            float uu =      xq[0] * w0.x;
            uu = fmaf(xq[1], w0.y, uu);
            uu = fmaf(xq[2], w0.z, uu);
            uu = fmaf(xq[3], w0.w, uu);
            uu = fmaf(xq[4], w1.x, uu);
            uu = fmaf(xq[5], w1.y, uu);
            uu = fmaf(xq[6], w1.z, uu);
            uu = fmaf(xq[7], w1.w, uu);
            u[c] = uu;
        }
        // Softmax without max-subtraction: |u*a| < ~40 -> exp2 safely in range
        // (logits bounded since |A| <= 2 and |u| <~ 15; validated absmax=0 in R3).
        float Z = 0.f;
#pragma unroll
        for (int c = 0; c < NCAPS; ++c) {
            const float ee = exp2f(u[c] * a2[c]);
            e[c] = ee;
            Z += ee;
        }
        const float rz = __builtin_amdgcn_rcpf(Z);
#pragma unroll
        for (int c = 0; c < NCAPS; ++c)
            acc[c] = fmaf(e[c] * rz, u[c], acc[c]);
    }

    float* pout = P + (((size_t)blockIdx.x * BATCH + b) * NCAPS) * NO + o;
#pragma unroll
    for (int c = 0; c < NCAPS; ++c) pout[c * NO] = acc[c];
}

// Reduce partials over chunks, squash, update A; emit V on the final iteration.
__global__ void caps_reduce_squash(const float* __restrict__ P,
                                   float* __restrict__ A,
                                   float* __restrict__ out,
                                   int nchunk)
{
    __shared__ float sm[256];
    const int bc  = blockIdx.x;     // b*NCAPS + c
    const int tid = threadIdx.x;    // 256 = 16 j x 16 o
    const int o = tid & 15;
    const int j = tid >> 4;
    float s = 0.f;
    for (int t = j; t < nchunk; t += 16)
        s += P[((size_t)t * (BATCH * NCAPS) + bc) * NO + o];
    sm[tid] = s;
    __syncthreads();
    if (tid < 16) {
        float S = 0.f;
#pragma unroll
        for (int k = 0; k < 16; ++k) S += sm[tid + 16 * k];
        float sq = S * S;
#pragma unroll
        for (int d = 8; d >= 1; d >>= 1) sq += __shfl_xor(sq, d, 16);
        const float scale = sq / ((1.f + sq) * sqrtf(sq));
        const float V = S * scale;
        const int idx = bc * NO + tid;
        A[idx] += V;
        if (out) out[idx] = V;
    }
}

__global__ void caps_zero(float* __restrict__ p, int n)
{
    const int i = blockIdx.x * blockDim.x + threadIdx.x;
    if (i < n) p[i] = 0.f;
}

extern "C" void kernel_launch(void* const* d_in, const int* in_sizes, int n_in,
                              void* d_out, int out_size, void* d_ws, size_t ws_size,
                              hipStream_t stream)
{
    const float* x = (const float*)d_in[0];   // [32][4608][8]
    const float* W = (const float*)d_in[1];   // [32][4608][8][16]
    float* out = (float*)d_out;               // [32][32][16]

    float* A = (float*)d_ws;                        // 16384 floats
    float* P = A + BATCH * NCAPS * NO;

    // Largest power-of-two chunk count whose partial buffer fits the workspace.
    // 512 -> rb=9, grid 512 = 2 blocks/CU.
    int nchunk = 512;
    while (nchunk > 128 &&
           (size_t)(nchunk + 1) * (BATCH * NCAPS * NO) * sizeof(float) > ws_size)
        nchunk >>= 1;
    const int rb = NR / nchunk;

    caps_zero<<<(BATCH * NCAPS * NO + 255) / 256, 256, 0, stream>>>(A, BATCH * NCAPS * NO);

    for (int it = 0; it < 3; ++it) {
        caps_route_pass<<<nchunk, 512, 0, stream>>>(x, W, A, P, rb);
        caps_reduce_squash<<<BATCH * NCAPS, 256, 0, stream>>>(
            P, A, it == 2 ? out : nullptr, nchunk);
    }
}

// Round 5
// 332.705 us; speedup vs baseline: 3.1120x; 1.0890x over previous
//
#include <hip/hip_runtime.h>

#define BATCH 32
#define NCAPS 32
#define NR    4608
#define NI    8
#define NO    16
#define CSTR  200   // LDS floats per capsule row: o*12 layout + pad (2-way banks max everywhere)
#define MAXRB 36
#define L2E   1.44269504088896341f

// ---------------- fast path: compile-time RB, double-buffered W tile, 1 barrier/r ----------------
// Lane layout o-major: wave = 32 b x 2 o -> W LDS reads are 2-address broadcasts,
// x LDS reads are 32-consecutive-dword broadcasts. P layout [chunk][b][o][c] so each
// thread stores a contiguous 128B c-row (full-line dirty -> no write amplification).
template<int RB, bool FIRST>
__global__ __launch_bounds__(512, 2) void caps_route_fast(
    const float* __restrict__ x,    // [B][R][I]
    const float* __restrict__ W,    // [C][R][I][O]
    const float* __restrict__ A,    // [B][C][O]
    float* __restrict__ P)          // [nchunk][B][O][C]
{
    __shared__ __align__(16) float Ws[2][NCAPS * CSTR];   // 51.2 KB
    __shared__ __align__(16) float xsT[NI][RB * BATCH];   // 9.2 KB @ RB=9

    const int t = threadIdx.x;
    const int b = t & 31;
    const int o = t >> 5;          // 0..15
    const int r0 = blockIdx.x * RB;

    float a2[NCAPS];
    if (!FIRST) {
#pragma unroll
        for (int c = 0; c < NCAPS; ++c)
            a2[c] = A[(b * NCAPS + c) * NO + o] * L2E;
    }
    float acc[NCAPS];
#pragma unroll
    for (int c = 0; c < NCAPS; ++c) acc[c] = 0.f;

    // Stage x transposed: xsT[i][rr*32+b] (conflict-free writes and reads).
    for (int s = t; s < RB * BATCH; s += 512) {
        const int rr = s >> 5, bb = s & 31;
        const float* xp = &x[((size_t)bb * NR + r0 + rr) * NI];
        const float4 v0 = *(const float4*)xp;
        const float4 v1 = *(const float4*)(xp + 4);
        const float tmp[8] = {v0.x, v0.y, v0.z, v0.w, v1.x, v1.y, v1.z, v1.w};
#pragma unroll
        for (int i = 0; i < NI; ++i) xsT[i][s] = tmp[i];
    }

    // W staging role: 4 consecutive capsules x 16 segments per wave (coalesced 512B/capsule).
    const int cs  = t >> 4;
    const int seg = t & 15;
    const int iw  = seg >> 1;
    const int ob  = (seg & 1) * 8;
    const float* wsrc = W + ((size_t)cs * NR + r0) * (NI * NO) + seg * 8;

    // Prologue: stage r0 into buf0, prefetch r1 into regs.
    {
        const float4 s0 = *(const float4*)wsrc;
        const float4 s1 = *(const float4*)(wsrc + 4);
        const float tmp[8] = {s0.x, s0.y, s0.z, s0.w, s1.x, s1.y, s1.z, s1.w};
#pragma unroll
        for (int k = 0; k < 8; ++k)
            Ws[0][cs * CSTR + (ob + k) * 12 + iw] = tmp[k];
    }
    float4 pf0 = {}, pf1 = {};
    if (RB > 1) {
        pf0 = *(const float4*)(wsrc + NI * NO);
        pf1 = *(const float4*)(wsrc + NI * NO + 4);
    }
    __syncthreads();

#pragma unroll 1
    for (int rr = 0; rr < RB; ++rr) {
        const int cur = rr & 1;

        // Write next W tile into the other buffer (no barrier needed: disjoint buf),
        // then issue the global prefetch for rr+2 so its latency hides under compute.
        if (rr + 1 < RB) {
            const float tmp[8] = {pf0.x, pf0.y, pf0.z, pf0.w,
                                  pf1.x, pf1.y, pf1.z, pf1.w};
#pragma unroll
            for (int k = 0; k < 8; ++k)
                Ws[cur ^ 1][cs * CSTR + (ob + k) * 12 + iw] = tmp[k];
            if (rr + 2 < RB) {
                const float* wn = wsrc + (size_t)(rr + 2) * (NI * NO);
                pf0 = *(const float4*)wn;
                pf1 = *(const float4*)(wn + 4);
            }
        }

        float xq[NI];
#pragma unroll
        for (int i = 0; i < NI; ++i) xq[i] = xsT[i][rr * 32 + b];

        const float* bp = &Ws[cur][o * 12];
        if (FIRST) {
            // A == 0 -> softmax uniform: acc += u (scaled by 1/32 at the store).
#pragma unroll
            for (int c = 0; c < NCAPS; ++c) {
                const float* wp = bp + c * CSTR;
                const float4 w0 = *(const float4*)wp;
                const float4 w1 = *(const float4*)(wp + 4);
                float uu =      xq[0] * w0.x;
                uu = fmaf(xq[1], w0.y, uu);
                uu = fmaf(xq[2], w0.z, uu);
                uu = fmaf(xq[3], w0.w, uu);
                uu = fmaf(xq[4], w1.x, uu);
                uu = fmaf(xq[5], w1.y, uu);
                uu = fmaf(xq[6], w1.z, uu);
                uu = fmaf(xq[7], w1.w, uu);
                acc[c] += uu;
            }
        } else {
            float tt[NCAPS];
            float Z = 0.f;
#pragma unroll
            for (int c = 0; c < NCAPS; ++c) {
                const float* wp = bp + c * CSTR;
                const float4 w0 = *(const float4*)wp;
                const float4 w1 = *(const float4*)(wp + 4);
                float uu =      xq[0] * w0.x;
                uu = fmaf(xq[1], w0.y, uu);
                uu = fmaf(xq[2], w0.z, uu);
                uu = fmaf(xq[3], w0.w, uu);
                uu = fmaf(xq[4], w1.x, uu);
                uu = fmaf(xq[5], w1.y, uu);
                uu = fmaf(xq[6], w1.z, uu);
                uu = fmaf(xq[7], w1.w, uu);
                // |u*a2| bounded (|A|<=3, |u|<~15): exp2 in range without max-sub.
                const float ee = exp2f(uu * a2[c]);
                Z += ee;
                tt[c] = ee * uu;
            }
            const float rz = __builtin_amdgcn_rcpf(Z);
#pragma unroll
            for (int c = 0; c < NCAPS; ++c)
                acc[c] = fmaf(tt[c], rz, acc[c]);
        }
        __syncthreads();
    }

    // Coalesced epilogue: this thread owns P[blk][b][o][0..31] (128B contiguous).
    float* pout = P + (((size_t)blockIdx.x * BATCH + b) * NO + o) * NCAPS;
#pragma unroll
    for (int q = 0; q < NCAPS / 4; ++q) {
        float4 v;
        v.x = acc[4 * q + 0]; v.y = acc[4 * q + 1];
        v.z = acc[4 * q + 2]; v.w = acc[4 * q + 3];
        if (FIRST) { v.x *= 0.03125f; v.y *= 0.03125f; v.z *= 0.03125f; v.w *= 0.03125f; }
        *(float4*)(pout + 4 * q) = v;
    }
}

// ---------------- generic fallback: runtime rb, single-buffered (R4 structure) ----------------
__global__ __launch_bounds__(512, 2) void caps_route_generic(
    const float* __restrict__ x, const float* __restrict__ W,
    const float* __restrict__ A, float* __restrict__ P, int rb)
{
    __shared__ __align__(16) float Ws[NCAPS * CSTR];
    __shared__ __align__(16) float xsT[NI * MAXRB * BATCH];

    const int t = threadIdx.x;
    const int b = t & 31;
    const int o = t >> 5;
    const int r0 = blockIdx.x * rb;
    const int rbs = rb * BATCH;

    float a2[NCAPS];
#pragma unroll
    for (int c = 0; c < NCAPS; ++c)
        a2[c] = A[(b * NCAPS + c) * NO + o] * L2E;
    float acc[NCAPS];
#pragma unroll
    for (int c = 0; c < NCAPS; ++c) acc[c] = 0.f;

    for (int s = t; s < rbs; s += 512) {
        const int rr = s >> 5, bb = s & 31;
        const float4 v0 = *(const float4*)&x[((size_t)bb * NR + r0 + rr) * NI];
        const float4 v1 = *(const float4*)&x[((size_t)bb * NR + r0 + rr) * NI + 4];
        const float tmp[8] = {v0.x, v0.y, v0.z, v0.w, v1.x, v1.y, v1.z, v1.w};
#pragma unroll
        for (int i = 0; i < NI; ++i) xsT[i * rbs + s] = tmp[i];
    }

    const int cs  = t >> 4;
    const int seg = t & 15;
    const int iw  = seg >> 1;
    const int ob  = (seg & 1) * 8;
    const float* wsrc = W + ((size_t)cs * NR + r0) * (NI * NO) + seg * 8;
    float4 pf0 = *(const float4*)wsrc;
    float4 pf1 = *(const float4*)(wsrc + 4);

    for (int rr = 0; rr < rb; ++rr) {
        __syncthreads();
        {
            const float tmp[8] = {pf0.x, pf0.y, pf0.z, pf0.w,
                                  pf1.x, pf1.y, pf1.z, pf1.w};
#pragma unroll
            for (int k = 0; k < 8; ++k)
                Ws[cs * CSTR + (ob + k) * 12 + iw] = tmp[k];
        }
        if (rr + 1 < rb) {
            wsrc += NI * NO;
            pf0 = *(const float4*)wsrc;
            pf1 = *(const float4*)(wsrc + 4);
        }
        __syncthreads();

        float xq[NI];
#pragma unroll
        for (int i = 0; i < NI; ++i) xq[i] = xsT[i * rbs + rr * 32 + b];

        float tt[NCAPS];
        float Z = 0.f;
        const float* bp = &Ws[o * 12];
#pragma unroll
        for (int c = 0; c < NCAPS; ++c) {
            const float* wp = bp + c * CSTR;
            const float4 w0 = *(const float4*)wp;
            const float4 w1 = *(const float4*)(wp + 4);
            float uu =      xq[0] * w0.x;
            uu = fmaf(xq[1], w0.y, uu);
            uu = fmaf(xq[2], w0.z, uu);
            uu = fmaf(xq[3], w0.w, uu);
            uu = fmaf(xq[4], w1.x, uu);
            uu = fmaf(xq[5], w1.y, uu);
            uu = fmaf(xq[6], w1.z, uu);
            uu = fmaf(xq[7], w1.w, uu);
            const float ee = exp2f(uu * a2[c]);
            Z += ee;
            tt[c] = ee * uu;
        }
        const float rz = __builtin_amdgcn_rcpf(Z);
#pragma unroll
        for (int c = 0; c < NCAPS; ++c)
            acc[c] = fmaf(tt[c], rz, acc[c]);
    }

    float* pout = P + (((size_t)blockIdx.x * BATCH + b) * NO + o) * NCAPS;
#pragma unroll
    for (int q = 0; q < NCAPS / 4; ++q) {
        float4 v;
        v.x = acc[4 * q + 0]; v.y = acc[4 * q + 1];
        v.z = acc[4 * q + 2]; v.w = acc[4 * q + 3];
        *(float4*)(pout + 4 * q) = v;
    }
}

// Reduce partials over chunks, squash, update A; emit V on the final iteration.
// P layout [chunk][b][o][c].
__global__ void caps_reduce_squash(const float* __restrict__ P,
                                   float* __restrict__ A,
                                   float* __restrict__ out,
                                   int nchunk)
{
    __shared__ float sm[256];
    const int bc  = blockIdx.x;     // b*NCAPS + c
    const int b   = bc >> 5;
    const int c   = bc & 31;
    const int tid = threadIdx.x;    // 256 = 16 j x 16 o
    const int o = tid & 15;
    const int j = tid >> 4;
    float s = 0.f;
    for (int tch = j; tch < nchunk; tch += 16)
        s += P[(((size_t)tch * BATCH + b) * NO + o) * NCAPS + c];
    sm[tid] = s;
    __syncthreads();
    if (tid < 16) {
        float S = 0.f;
#pragma unroll
        for (int k = 0; k < 16; ++k) S += sm[tid + 16 * k];
        float sq = S * S;
#pragma unroll
        for (int d = 8; d >= 1; d >>= 1) sq += __shfl_xor(sq, d, 16);
        const float scale = sq / ((1.f + sq) * sqrtf(sq));
        const float V = S * scale;
        const int idx = bc * NO + tid;
        A[idx] += V;
        if (out) out[idx] = V;
    }
}

__global__ void caps_zero(float* __restrict__ p, int n)
{
    const int i = blockIdx.x * blockDim.x + threadIdx.x;
    if (i < n) p[i] = 0.f;
}

extern "C" void kernel_launch(void* const* d_in, const int* in_sizes, int n_in,
                              void* d_out, int out_size, void* d_ws, size_t ws_size,
                              hipStream_t stream)
{
    const float* x = (const float*)d_in[0];   // [32][4608][8]
    const float* W = (const float*)d_in[1];   // [32][4608][8][16]
    float* out = (float*)d_out;               // [32][32][16]

    float* A = (float*)d_ws;                  // 16384 floats
    float* P = A + BATCH * NCAPS * NO;

    const size_t elem = (size_t)BATCH * NCAPS * NO;   // 16384
    caps_zero<<<(int)((elem + 255) / 256), 256, 0, stream>>>(A, (int)elem);

    if ((size_t)(512 + 1) * elem * sizeof(float) <= ws_size) {
        // Fast path: nchunk=512, RB=9, 2 blocks/CU.
        caps_route_fast<9, true><<<512, 512, 0, stream>>>(x, W, A, P);
        caps_reduce_squash<<<BATCH * NCAPS, 256, 0, stream>>>(P, A, nullptr, 512);
        caps_route_fast<9, false><<<512, 512, 0, stream>>>(x, W, A, P);
        caps_reduce_squash<<<BATCH * NCAPS, 256, 0, stream>>>(P, A, nullptr, 512);
        caps_route_fast<9, false><<<512, 512, 0, stream>>>(x, W, A, P);
        caps_reduce_squash<<<BATCH * NCAPS, 256, 0, stream>>>(P, A, out, 512);
    } else {
        int nchunk = 256;
        while (nchunk > 128 &&
               (size_t)(nchunk + 1) * elem * sizeof(float) > ws_size)
            nchunk >>= 1;
        const int rb = NR / nchunk;
        for (int it = 0; it < 3; ++it) {
            caps_route_generic<<<nchunk, 512, 0, stream>>>(x, W, A, P, rb);
            caps_reduce_squash<<<BATCH * NCAPS, 256, 0, stream>>>(
                P, A, it == 2 ? out : nullptr, nchunk);
        }
    }
}

// Round 6
// 252.265 us; speedup vs baseline: 4.1043x; 1.3189x over previous
//
#include <hip/hip_runtime.h>

#define BATCH 32
#define NCAPS 32
#define NR    4608
#define NI    8
#define NO    16
#define CSTR  200   // LDS floats per capsule row (o*12 + i layout); 800B, 16B aligned
#define MAXRB 36
#define L2E   1.44269504088896341f

// ---------------- fast path ----------------
// 1024 threads: thread = (b-pair w = t>>6, o = (t>>2)&15, c-quarter cq = t&3).
// Each thread computes u for 2 b x 8 c x 1 o -> every W byte read from LDS feeds
// 2 FMAs (halves the LDS-return traffic that capped R5 at 47% VALUBusy).
// Softmax over c: local 8-sum + 2x shfl_xor across the 4 cq lanes (lane[1:0]=cq).
// Grid 256 = 1 block/CU (16 waves), rb = 18. W double-buffered, 1 barrier/r.
template<int RB, bool FIRST>
__global__ __launch_bounds__(1024, 4) void caps_route_fast(
    const float* __restrict__ x,    // [B][R][I]
    const float* __restrict__ W,    // [C][R][I][O]
    const float* __restrict__ A,    // [B][C][O]
    float* __restrict__ P)          // [nchunk][B][O][C]
{
    __shared__ __align__(16) float Ws[2][NCAPS * CSTR];   // 51.2 KB
    __shared__ __align__(16) float xsT[NI][RB * BATCH];   // 18.4 KB @ RB=18

    const int t  = threadIdx.x;
    const int cq = t & 3;             // c in [8cq, 8cq+8)
    const int o  = (t >> 2) & 15;
    const int w  = t >> 6;            // wave id = b pair
    const int b0 = 2 * w;
    const int r0 = blockIdx.x * RB;

    float a2[2][8];
    if (!FIRST) {
#pragma unroll
        for (int bb = 0; bb < 2; ++bb)
#pragma unroll
            for (int cl = 0; cl < 8; ++cl)
                a2[bb][cl] = A[((b0 + bb) * NCAPS + 8 * cq + cl) * NO + o] * L2E;
    }
    float acc[2][8];
#pragma unroll
    for (int bb = 0; bb < 2; ++bb)
#pragma unroll
        for (int cl = 0; cl < 8; ++cl) acc[bb][cl] = 0.f;

    // Stage x transposed: xsT[i][rr*32+b].
    for (int s = t; s < RB * BATCH; s += 1024) {
        const int rr = s >> 5, bb = s & 31;
        const float* xp = &x[((size_t)bb * NR + r0 + rr) * NI];
        const float4 v0 = *(const float4*)xp;
        const float4 v1 = *(const float4*)(xp + 4);
        const float tmp[8] = {v0.x, v0.y, v0.z, v0.w, v1.x, v1.y, v1.z, v1.w};
#pragma unroll
        for (int i = 0; i < NI; ++i) xsT[i][s] = tmp[i];
    }

    // W staging: 1 float4 per thread per r. c_st = t>>5, part = t&31.
    const int c_st = t >> 5;
    const int part = t & 31;
    const int i_st = part >> 2;
    const int o0   = (part & 3) * 4;
    const float* wsrc = W + ((size_t)c_st * NR + r0) * (NI * NO) + part * 4;

    // Prologue: stage r0 into buf0, prefetch r1.
    {
        const float4 s0 = *(const float4*)wsrc;
        float* d = &Ws[0][c_st * CSTR + o0 * 12 + i_st];
        d[0] = s0.x; d[12] = s0.y; d[24] = s0.z; d[36] = s0.w;
    }
    float4 pf = {};
    if (RB > 1) pf = *(const float4*)(wsrc + NI * NO);
    __syncthreads();

#pragma unroll 1
    for (int rr = 0; rr < RB; ++rr) {
        const int cur = rr & 1;

        // Stage next tile into the other buffer; prefetch rr+2 (latency hides
        // under this iteration's compute).
        if (rr + 1 < RB) {
            float* d = &Ws[cur ^ 1][c_st * CSTR + o0 * 12 + i_st];
            d[0] = pf.x; d[12] = pf.y; d[24] = pf.z; d[36] = pf.w;
            if (rr + 2 < RB)
                pf = *(const float4*)(wsrc + (size_t)(rr + 2) * (NI * NO));
        }

        // x for this thread's 2 b's: wave-uniform broadcast reads (b0 = 2w).
        float xq[2][NI];
#pragma unroll
        for (int i = 0; i < NI; ++i) {
            const float2 xv = *(const float2*)&xsT[i][rr * 32 + b0];
            xq[0][i] = xv.x; xq[1][i] = xv.y;
        }

        const float* wb = &Ws[cur][(8 * cq) * CSTR + o * 12];
        if (FIRST) {
            // A == 0 -> softmax uniform: acc += u (1/32 folded into the store).
#pragma unroll
            for (int cl = 0; cl < 8; ++cl) {
                const float* wp = wb + cl * CSTR;
                const float4 w0 = *(const float4*)wp;
                const float4 w1 = *(const float4*)(wp + 4);
#pragma unroll
                for (int bb = 0; bb < 2; ++bb) {
                    float u =      xq[bb][0] * w0.x;
                    u = fmaf(xq[bb][1], w0.y, u);
                    u = fmaf(xq[bb][2], w0.z, u);
                    u = fmaf(xq[bb][3], w0.w, u);
                    u = fmaf(xq[bb][4], w1.x, u);
                    u = fmaf(xq[bb][5], w1.y, u);
                    u = fmaf(xq[bb][6], w1.z, u);
                    u = fmaf(xq[bb][7], w1.w, u);
                    acc[bb][cl] += u;
                }
            }
        } else {
            float tt[2][8];
            float z0 = 0.f, z1 = 0.f;
#pragma unroll
            for (int cl = 0; cl < 8; ++cl) {
                const float* wp = wb + cl * CSTR;
                const float4 w0 = *(const float4*)wp;
                const float4 w1 = *(const float4*)(wp + 4);
                float u0 =      xq[0][0] * w0.x;
                u0 = fmaf(xq[0][1], w0.y, u0);
                u0 = fmaf(xq[0][2], w0.z, u0);
                u0 = fmaf(xq[0][3], w0.w, u0);
                u0 = fmaf(xq[0][4], w1.x, u0);
                u0 = fmaf(xq[0][5], w1.y, u0);
                u0 = fmaf(xq[0][6], w1.z, u0);
                u0 = fmaf(xq[0][7], w1.w, u0);
                float u1 =      xq[1][0] * w0.x;
                u1 = fmaf(xq[1][1], w0.y, u1);
                u1 = fmaf(xq[1][2], w0.z, u1);
                u1 = fmaf(xq[1][3], w0.w, u1);
                u1 = fmaf(xq[1][4], w1.x, u1);
                u1 = fmaf(xq[1][5], w1.y, u1);
                u1 = fmaf(xq[1][6], w1.z, u1);
                u1 = fmaf(xq[1][7], w1.w, u1);
                // logits bounded (|A|<=3, |u|<~15): exp2 in range without max-sub
                // (validated absmax=0 in R3-R5).
                const float e0 = exp2f(u0 * a2[0][cl]);
                const float e1 = exp2f(u1 * a2[1][cl]);
                z0 += e0; z1 += e1;
                tt[0][cl] = e0 * u0;
                tt[1][cl] = e1 * u1;
            }
            // Full Z over 32 c: sum across the 4 cq lanes (lane bits [1:0]).
            z0 += __shfl_xor(z0, 1); z0 += __shfl_xor(z0, 2);
            z1 += __shfl_xor(z1, 1); z1 += __shfl_xor(z1, 2);
            const float rz0 = __builtin_amdgcn_rcpf(z0);
            const float rz1 = __builtin_amdgcn_rcpf(z1);
#pragma unroll
            for (int cl = 0; cl < 8; ++cl) {
                acc[0][cl] = fmaf(tt[0][cl], rz0, acc[0][cl]);
                acc[1][cl] = fmaf(tt[1][cl], rz1, acc[1][cl]);
            }
        }
        __syncthreads();
    }

    // Epilogue: P[blk][b][o][8cq..8cq+7] for both b's; lanes tile c then o ->
    // 2KB contiguous per wave per b.
#pragma unroll
    for (int bb = 0; bb < 2; ++bb) {
        float* pout = P + (((size_t)blockIdx.x * BATCH + b0 + bb) * NO + o) * NCAPS + 8 * cq;
        float4 v0, v1;
        v0.x = acc[bb][0]; v0.y = acc[bb][1]; v0.z = acc[bb][2]; v0.w = acc[bb][3];
        v1.x = acc[bb][4]; v1.y = acc[bb][5]; v1.z = acc[bb][6]; v1.w = acc[bb][7];
        if (FIRST) {
            v0.x *= 0.03125f; v0.y *= 0.03125f; v0.z *= 0.03125f; v0.w *= 0.03125f;
            v1.x *= 0.03125f; v1.y *= 0.03125f; v1.z *= 0.03125f; v1.w *= 0.03125f;
        }
        *(float4*)pout = v0;
        *(float4*)(pout + 4) = v1;
    }
}

// ---------------- generic fallback (R5 structure, validated) ----------------
__global__ __launch_bounds__(512, 2) void caps_route_generic(
    const float* __restrict__ x, const float* __restrict__ W,
    const float* __restrict__ A, float* __restrict__ P, int rb)
{
    __shared__ __align__(16) float Ws[NCAPS * CSTR];
    __shared__ __align__(16) float xsT[NI * MAXRB * BATCH];

    const int t = threadIdx.x;
    const int b = t & 31;
    const int o = t >> 5;
    const int r0 = blockIdx.x * rb;
    const int rbs = rb * BATCH;

    float a2[NCAPS];
#pragma unroll
    for (int c = 0; c < NCAPS; ++c)
        a2[c] = A[(b * NCAPS + c) * NO + o] * L2E;
    float acc[NCAPS];
#pragma unroll
    for (int c = 0; c < NCAPS; ++c) acc[c] = 0.f;

    for (int s = t; s < rbs; s += 512) {
        const int rr = s >> 5, bb = s & 31;
        const float4 v0 = *(const float4*)&x[((size_t)bb * NR + r0 + rr) * NI];
        const float4 v1 = *(const float4*)&x[((size_t)bb * NR + r0 + rr) * NI + 4];
        const float tmp[8] = {v0.x, v0.y, v0.z, v0.w, v1.x, v1.y, v1.z, v1.w};
#pragma unroll
        for (int i = 0; i < NI; ++i) xsT[i * rbs + s] = tmp[i];
    }

    const int cs  = t >> 4;
    const int seg = t & 15;
    const int iw  = seg >> 1;
    const int ob  = (seg & 1) * 8;
    const float* wsrc = W + ((size_t)cs * NR + r0) * (NI * NO) + seg * 8;
    float4 pf0 = *(const float4*)wsrc;
    float4 pf1 = *(const float4*)(wsrc + 4);

    for (int rr = 0; rr < rb; ++rr) {
        __syncthreads();
        {
            const float tmp[8] = {pf0.x, pf0.y, pf0.z, pf0.w,
                                  pf1.x, pf1.y, pf1.z, pf1.w};
#pragma unroll
            for (int k = 0; k < 8; ++k)
                Ws[cs * CSTR + (ob + k) * 12 + iw] = tmp[k];
        }
        if (rr + 1 < rb) {
            wsrc += NI * NO;
            pf0 = *(const float4*)wsrc;
            pf1 = *(const float4*)(wsrc + 4);
        }
        __syncthreads();

        float xq[NI];
#pragma unroll
        for (int i = 0; i < NI; ++i) xq[i] = xsT[i * rbs + rr * 32 + b];

        float tt[NCAPS];
        float Z = 0.f;
        const float* bp = &Ws[o * 12];
#pragma unroll
        for (int c = 0; c < NCAPS; ++c) {
            const float* wp = bp + c * CSTR;
            const float4 w0 = *(const float4*)wp;
            const float4 w1 = *(const float4*)(wp + 4);
            float uu =      xq[0] * w0.x;
            uu = fmaf(xq[1], w0.y, uu);
            uu = fmaf(xq[2], w0.z, uu);
            uu = fmaf(xq[3], w0.w, uu);
            uu = fmaf(xq[4], w1.x, uu);
            uu = fmaf(xq[5], w1.y, uu);
            uu = fmaf(xq[6], w1.z, uu);
            uu = fmaf(xq[7], w1.w, uu);
            const float ee = exp2f(uu * a2[c]);
            Z += ee;
            tt[c] = ee * uu;
        }
        const float rz = __builtin_amdgcn_rcpf(Z);
#pragma unroll
        for (int c = 0; c < NCAPS; ++c)
            acc[c] = fmaf(tt[c], rz, acc[c]);
    }

    float* pout = P + (((size_t)blockIdx.x * BATCH + b) * NO + o) * NCAPS;
#pragma unroll
    for (int q = 0; q < NCAPS / 4; ++q) {
        float4 v;
        v.x = acc[4 * q + 0]; v.y = acc[4 * q + 1];
        v.z = acc[4 * q + 2]; v.w = acc[4 * q + 3];
        *(float4*)(pout + 4 * q) = v;
    }
}

// Reduce partials over chunks, squash, update A; emit V on the final iteration.
// P layout [chunk][b][o][c].
__global__ void caps_reduce_squash(const float* __restrict__ P,
                                   float* __restrict__ A,
                                   float* __restrict__ out,
                                   int nchunk)
{
    __shared__ float sm[256];
    const int bc  = blockIdx.x;     // b*NCAPS + c
    const int b   = bc >> 5;
    const int c   = bc & 31;
    const int tid = threadIdx.x;    // 256 = 16 j x 16 o
    const int o = tid & 15;
    const int j = tid >> 4;
    float s = 0.f;
    for (int tch = j; tch < nchunk; tch += 16)
        s += P[(((size_t)tch * BATCH + b) * NO + o) * NCAPS + c];
    sm[tid] = s;
    __syncthreads();
    if (tid < 16) {
        float S = 0.f;
#pragma unroll
        for (int k = 0; k < 16; ++k) S += sm[tid + 16 * k];
        float sq = S * S;
#pragma unroll
        for (int d = 8; d >= 1; d >>= 1) sq += __shfl_xor(sq, d, 16);
        const float scale = sq / ((1.f + sq) * sqrtf(sq));
        const float V = S * scale;
        const int idx = bc * NO + tid;
        A[idx] += V;
        if (out) out[idx] = V;
    }
}

__global__ void caps_zero(float* __restrict__ p, int n)
{
    const int i = blockIdx.x * blockDim.x + threadIdx.x;
    if (i < n) p[i] = 0.f;
}

extern "C" void kernel_launch(void* const* d_in, const int* in_sizes, int n_in,
                              void* d_out, int out_size, void* d_ws, size_t ws_size,
                              hipStream_t stream)
{
    const float* x = (const float*)d_in[0];   // [32][4608][8]
    const float* W = (const float*)d_in[1];   // [32][4608][8][16]
    float* out = (float*)d_out;               // [32][32][16]

    float* A = (float*)d_ws;                  // 16384 floats
    float* P = A + BATCH * NCAPS * NO;

    const size_t elem = (size_t)BATCH * NCAPS * NO;   // 16384
    caps_zero<<<(int)((elem + 255) / 256), 256, 0, stream>>>(A, (int)elem);

    if ((size_t)(256 + 1) * elem * sizeof(float) <= ws_size) {
        // Fast path: nchunk=256 (grid = 1 block/CU), RB=18.
        caps_route_fast<18, true><<<256, 1024, 0, stream>>>(x, W, A, P);
        caps_reduce_squash<<<BATCH * NCAPS, 256, 0, stream>>>(P, A, nullptr, 256);
        caps_route_fast<18, false><<<256, 1024, 0, stream>>>(x, W, A, P);
        caps_reduce_squash<<<BATCH * NCAPS, 256, 0, stream>>>(P, A, nullptr, 256);
        caps_route_fast<18, false><<<256, 1024, 0, stream>>>(x, W, A, P);
        caps_reduce_squash<<<BATCH * NCAPS, 256, 0, stream>>>(P, A, out, 256);
    } else {
        int nchunk = 128;
        while (nchunk > 32 &&
               (size_t)(nchunk + 1) * elem * sizeof(float) > ws_size)
            nchunk >>= 1;
        const int rb = NR / nchunk;
        for (int it = 0; it < 3; ++it) {
            caps_route_generic<<<nchunk, 512, 0, stream>>>(x, W, A, P, rb);
            caps_reduce_squash<<<BATCH * NCAPS, 256, 0, stream>>>(
                P, A, it == 2 ? out : nullptr, nchunk);
        }
    }
}

// Round 7
// 187.060 us; speedup vs baseline: 5.5350x; 1.3486x over previous
//
#include <hip/hip_runtime.h>

#define BATCH 32
#define NCAPS 32
#define NR    4608
#define NI    8
#define NO    16
#define CSTR  200   // LDS floats per capsule row (o*12 + i layout)
#define MAXRB 36
#define L2E   1.44269504088896341f

typedef float f2 __attribute__((ext_vector_type(2)));

// ---------------- fast path ----------------
// 1024 threads: thread = (b-pair w = t>>6, o = (t>>2)&15, c-quarter cq = t&3).
// The b-pair lives in the two halves of packed float2s -> v_pk_fma_f32 halves
// the VALU issue count of the inner loop (occupancy is VGPR-capped at ~16
// waves/CU for this footprint, so per-wave issue efficiency is the lever).
template<int RB, bool FIRST>
__global__ __launch_bounds__(1024, 4) void caps_route_fast(
    const float* __restrict__ x,    // [B][R][I]
    const float* __restrict__ W,    // [C][R][I][O]
    const float* __restrict__ A,    // [B][C][O]
    float* __restrict__ P)          // [nchunk][B][O][C]
{
    __shared__ __align__(16) float Ws[2][NCAPS * CSTR];   // 51.2 KB
    __shared__ __align__(16) f2    xP[RB][BATCH / 2][NI]; // 9.2 KB @ RB=18

    const int t  = threadIdx.x;
    const int cq = t & 3;             // c in [8cq, 8cq+8)
    const int o  = (t >> 2) & 15;
    const int w  = t >> 6;            // wave id = b pair
    const int b0 = 2 * w;
    const int r0 = blockIdx.x * RB;

    f2 a2[8];
    if (!FIRST) {
#pragma unroll
        for (int cl = 0; cl < 8; ++cl) {
            a2[cl].x = A[((b0 + 0) * NCAPS + 8 * cq + cl) * NO + o] * L2E;
            a2[cl].y = A[((b0 + 1) * NCAPS + 8 * cq + cl) * NO + o] * L2E;
        }
    }
    f2 acc[8];
#pragma unroll
    for (int cl = 0; cl < 8; ++cl) acc[cl] = (f2)0.f;

    // Stage x pre-interleaved by b-pair: xP[rr][w][i] = {x[2w][i], x[2w+1][i]}.
    for (int s = t; s < RB * (BATCH / 2); s += 1024) {
        const int rr = s >> 4, bp = s & 15;
        const float* xp0 = &x[((size_t)(2 * bp + 0) * NR + r0 + rr) * NI];
        const float* xp1 = &x[((size_t)(2 * bp + 1) * NR + r0 + rr) * NI];
        const float4 a0 = *(const float4*)xp0;
        const float4 a1 = *(const float4*)(xp0 + 4);
        const float4 c0 = *(const float4*)xp1;
        const float4 c1 = *(const float4*)(xp1 + 4);
        f2* d = &xP[rr][bp][0];
        d[0] = f2{a0.x, c0.x}; d[1] = f2{a0.y, c0.y};
        d[2] = f2{a0.z, c0.z}; d[3] = f2{a0.w, c0.w};
        d[4] = f2{a1.x, c1.x}; d[5] = f2{a1.y, c1.y};
        d[6] = f2{a1.z, c1.z}; d[7] = f2{a1.w, c1.w};
    }

    // W staging: 1 float4 per thread per r. c_st = t>>5, part = t&31.
    const int c_st = t >> 5;
    const int part = t & 31;
    const int i_st = part >> 2;
    const int o0   = (part & 3) * 4;
    const float* wsrc = W + ((size_t)c_st * NR + r0) * (NI * NO) + part * 4;

    // Prologue: stage r0 into buf0, prefetch r1.
    {
        const float4 s0 = *(const float4*)wsrc;
        float* d = &Ws[0][c_st * CSTR + o0 * 12 + i_st];
        d[0] = s0.x; d[12] = s0.y; d[24] = s0.z; d[36] = s0.w;
    }
    float4 pf = {};
    if (RB > 1) pf = *(const float4*)(wsrc + NI * NO);
    __syncthreads();

#pragma unroll 1
    for (int rr = 0; rr < RB; ++rr) {
        const int cur = rr & 1;

        // Stage next tile into the other buffer; prefetch rr+2.
        if (rr + 1 < RB) {
            float* d = &Ws[cur ^ 1][c_st * CSTR + o0 * 12 + i_st];
            d[0] = pf.x; d[12] = pf.y; d[24] = pf.z; d[36] = pf.w;
            if (rr + 2 < RB)
                pf = *(const float4*)(wsrc + (size_t)(rr + 2) * (NI * NO));
        }

        // x pair for this wave: broadcast LDS reads (b128-mergeable).
        f2 xq[NI];
        {
            const f2* xv = &xP[rr][w][0];
#pragma unroll
            for (int i = 0; i < NI; ++i) xq[i] = xv[i];
        }

        const float* wb = &Ws[cur][(8 * cq) * CSTR + o * 12];
        if (FIRST) {
            // A == 0 -> softmax uniform: acc += u (1/32 folded into the store).
#pragma unroll
            for (int cl = 0; cl < 8; ++cl) {
                const float* wp = wb + cl * CSTR;
                const float4 w0 = *(const float4*)wp;
                const float4 w1 = *(const float4*)(wp + 4);
                f2 u2 = xq[0] * w0.x;
                u2 += xq[1] * w0.y;
                u2 += xq[2] * w0.z;
                u2 += xq[3] * w0.w;
                u2 += xq[4] * w1.x;
                u2 += xq[5] * w1.y;
                u2 += xq[6] * w1.z;
                u2 += xq[7] * w1.w;
                acc[cl] += u2;
            }
        } else {
            f2 tt[8];
            f2 Z = (f2)0.f;
#pragma unroll
            for (int cl = 0; cl < 8; ++cl) {
                const float* wp = wb + cl * CSTR;
                const float4 w0 = *(const float4*)wp;
                const float4 w1 = *(const float4*)(wp + 4);
                f2 u2 = xq[0] * w0.x;
                u2 += xq[1] * w0.y;
                u2 += xq[2] * w0.z;
                u2 += xq[3] * w0.w;
                u2 += xq[4] * w1.x;
                u2 += xq[5] * w1.y;
                u2 += xq[6] * w1.z;
                u2 += xq[7] * w1.w;
                // logits bounded (|A|<=3, |u|<~15): exp2 in range without
                // max-subtraction (validated absmax=0 in R3-R6).
                const f2 l2 = u2 * a2[cl];
                f2 e2;
                e2.x = exp2f(l2.x);
                e2.y = exp2f(l2.y);
                Z += e2;
                tt[cl] = e2 * u2;
            }
            // Full Z over 32 c: sum across the 4 cq lanes (lane bits [1:0]).
            Z.x += __shfl_xor(Z.x, 1); Z.x += __shfl_xor(Z.x, 2);
            Z.y += __shfl_xor(Z.y, 1); Z.y += __shfl_xor(Z.y, 2);
            f2 rz;
            rz.x = __builtin_amdgcn_rcpf(Z.x);
            rz.y = __builtin_amdgcn_rcpf(Z.y);
#pragma unroll
            for (int cl = 0; cl < 8; ++cl)
                acc[cl] += tt[cl] * rz;
        }
        __syncthreads();
    }

    // Epilogue: P[blk][b][o][8cq..8cq+7] for both b's of the pair.
#pragma unroll
    for (int bb = 0; bb < 2; ++bb) {
        float* pout = P + (((size_t)blockIdx.x * BATCH + b0 + bb) * NO + o) * NCAPS + 8 * cq;
        float4 v0, v1;
        v0.x = bb ? acc[0].y : acc[0].x; v0.y = bb ? acc[1].y : acc[1].x;
        v0.z = bb ? acc[2].y : acc[2].x; v0.w = bb ? acc[3].y : acc[3].x;
        v1.x = bb ? acc[4].y : acc[4].x; v1.y = bb ? acc[5].y : acc[5].x;
        v1.z = bb ? acc[6].y : acc[6].x; v1.w = bb ? acc[7].y : acc[7].x;
        if (FIRST) {
            v0.x *= 0.03125f; v0.y *= 0.03125f; v0.z *= 0.03125f; v0.w *= 0.03125f;
            v1.x *= 0.03125f; v1.y *= 0.03125f; v1.z *= 0.03125f; v1.w *= 0.03125f;
        }
        *(float4*)pout = v0;
        *(float4*)(pout + 4) = v1;
    }
}

// Stage-1 reduce: coalesced float4 column sums of P[256][16384] -> P2[16][16384].
__global__ __launch_bounds__(256) void caps_partial(const float* __restrict__ P,
                                                    float* __restrict__ P2)
{
    const int tid = threadIdx.x;
    const int ct  = blockIdx.x & 15;      // column tile (1024 floats)
    const int rg  = blockIdx.x >> 4;      // row group (16 rows)
    const size_t col = (size_t)ct * 1024 + tid * 4;
    const float* p = P + (size_t)rg * 16 * 16384 + col;
    float4 s = {0.f, 0.f, 0.f, 0.f};
#pragma unroll
    for (int k = 0; k < 16; ++k) {
        const float4 v = *(const float4*)(p + (size_t)k * 16384);
        s.x += v.x; s.y += v.y; s.z += v.z; s.w += v.w;
    }
    *(float4*)(P2 + (size_t)rg * 16384 + col) = s;
}

// Reduce partials over chunks, squash, update A; emit V on the final iteration.
// P layout [chunk][b][o][c].
__global__ void caps_reduce_squash(const float* __restrict__ P,
                                   float* __restrict__ A,
                                   float* __restrict__ out,
                                   int nchunk)
{
    __shared__ float sm[256];
    const int bc  = blockIdx.x;     // b*NCAPS + c
    const int b   = bc >> 5;
    const int c   = bc & 31;
    const int tid = threadIdx.x;    // 256 = 16 j x 16 o
    const int o = tid & 15;
    const int j = tid >> 4;
    float s = 0.f;
    for (int tch = j; tch < nchunk; tch += 16)
        s += P[(((size_t)tch * BATCH + b) * NO + o) * NCAPS + c];
    sm[tid] = s;
    __syncthreads();
    if (tid < 16) {
        float S = 0.f;
#pragma unroll
        for (int k = 0; k < 16; ++k) S += sm[tid + 16 * k];
        float sq = S * S;
#pragma unroll
        for (int d = 8; d >= 1; d >>= 1) sq += __shfl_xor(sq, d, 16);
        const float scale = sq / ((1.f + sq) * sqrtf(sq));
        const float V = S * scale;
        const int idx = bc * NO + tid;
        A[idx] += V;
        if (out) out[idx] = V;
    }
}

// ---------------- generic fallback (R6 structure, validated) ----------------
__global__ __launch_bounds__(512, 2) void caps_route_generic(
    const float* __restrict__ x, const float* __restrict__ W,
    const float* __restrict__ A, float* __restrict__ P, int rb)
{
    __shared__ __align__(16) float Ws[NCAPS * CSTR];
    __shared__ __align__(16) float xsT[NI * MAXRB * BATCH];

    const int t = threadIdx.x;
    const int b = t & 31;
    const int o = t >> 5;
    const int r0 = blockIdx.x * rb;
    const int rbs = rb * BATCH;

    float a2s[NCAPS];
#pragma unroll
    for (int c = 0; c < NCAPS; ++c)
        a2s[c] = A[(b * NCAPS + c) * NO + o] * L2E;
    float acc[NCAPS];
#pragma unroll
    for (int c = 0; c < NCAPS; ++c) acc[c] = 0.f;

    for (int s = t; s < rbs; s += 512) {
        const int rr = s >> 5, bb = s & 31;
        const float4 v0 = *(const float4*)&x[((size_t)bb * NR + r0 + rr) * NI];
        const float4 v1 = *(const float4*)&x[((size_t)bb * NR + r0 + rr) * NI + 4];
        const float tmp[8] = {v0.x, v0.y, v0.z, v0.w, v1.x, v1.y, v1.z, v1.w};
#pragma unroll
        for (int i = 0; i < NI; ++i) xsT[i * rbs + s] = tmp[i];
    }

    const int cs  = t >> 4;
    const int seg = t & 15;
    const int iw  = seg >> 1;
    const int ob  = (seg & 1) * 8;
    const float* wsrc = W + ((size_t)cs * NR + r0) * (NI * NO) + seg * 8;
    float4 pf0 = *(const float4*)wsrc;
    float4 pf1 = *(const float4*)(wsrc + 4);

    for (int rr = 0; rr < rb; ++rr) {
        __syncthreads();
        {
            const float tmp[8] = {pf0.x, pf0.y, pf0.z, pf0.w,
                                  pf1.x, pf1.y, pf1.z, pf1.w};
#pragma unroll
            for (int k = 0; k < 8; ++k)
                Ws[cs * CSTR + (ob + k) * 12 + iw] = tmp[k];
        }
        if (rr + 1 < rb) {
            wsrc += NI * NO;
            pf0 = *(const float4*)wsrc;
            pf1 = *(const float4*)(wsrc + 4);
        }
        __syncthreads();

        float xq[NI];
#pragma unroll
        for (int i = 0; i < NI; ++i) xq[i] = xsT[i * rbs + rr * 32 + b];

        float tt[NCAPS];
        float Z = 0.f;
        const float* bp = &Ws[o * 12];
#pragma unroll
        for (int c = 0; c < NCAPS; ++c) {
            const float* wp = bp + c * CSTR;
            const float4 w0 = *(const float4*)wp;
            const float4 w1 = *(const float4*)(wp + 4);
            float uu =      xq[0] * w0.x;
            uu = fmaf(xq[1], w0.y, uu);
            uu = fmaf(xq[2], w0.z, uu);
            uu = fmaf(xq[3], w0.w, uu);
            uu = fmaf(xq[4], w1.x, uu);
            uu = fmaf(xq[5], w1.y, uu);
            uu = fmaf(xq[6], w1.z, uu);
            uu = fmaf(xq[7], w1.w, uu);
            const float ee = exp2f(uu * a2s[c]);
            Z += ee;
            tt[c] = ee * uu;
        }
        const float rz = __builtin_amdgcn_rcpf(Z);
#pragma unroll
        for (int c = 0; c < NCAPS; ++c)
            acc[c] = fmaf(tt[c], rz, acc[c]);
    }

    float* pout = P + (((size_t)blockIdx.x * BATCH + b) * NO + o) * NCAPS;
#pragma unroll
    for (int q = 0; q < NCAPS / 4; ++q) {
        float4 v;
        v.x = acc[4 * q + 0]; v.y = acc[4 * q + 1];
        v.z = acc[4 * q + 2]; v.w = acc[4 * q + 3];
        *(float4*)(pout + 4 * q) = v;
    }
}

__global__ void caps_zero(float* __restrict__ p, int n)
{
    const int i = blockIdx.x * blockDim.x + threadIdx.x;
    if (i < n) p[i] = 0.f;
}

extern "C" void kernel_launch(void* const* d_in, const int* in_sizes, int n_in,
                              void* d_out, int out_size, void* d_ws, size_t ws_size,
                              hipStream_t stream)
{
    const float* x = (const float*)d_in[0];   // [32][4608][8]
    const float* W = (const float*)d_in[1];   // [32][4608][8][16]
    float* out = (float*)d_out;               // [32][32][16]

    float* A  = (float*)d_ws;                 // 16384 floats
    float* P  = A + BATCH * NCAPS * NO;       // 256 * 16384 floats
    float* P2 = P + (size_t)256 * BATCH * NCAPS * NO;   // 16 * 16384 floats

    const size_t elem = (size_t)BATCH * NCAPS * NO;   // 16384
    caps_zero<<<(int)((elem + 255) / 256), 256, 0, stream>>>(A, (int)elem);

    if ((1 + 256 + 16) * elem * sizeof(float) <= ws_size) {
        // Fast path: nchunk=256 (1 block/CU), RB=18, two-stage reduce.
        caps_route_fast<18, true><<<256, 1024, 0, stream>>>(x, W, A, P);
        caps_partial<<<256, 256, 0, stream>>>(P, P2);
        caps_reduce_squash<<<BATCH * NCAPS, 256, 0, stream>>>(P2, A, nullptr, 16);
        caps_route_fast<18, false><<<256, 1024, 0, stream>>>(x, W, A, P);
        caps_partial<<<256, 256, 0, stream>>>(P, P2);
        caps_reduce_squash<<<BATCH * NCAPS, 256, 0, stream>>>(P2, A, nullptr, 16);
        caps_route_fast<18, false><<<256, 1024, 0, stream>>>(x, W, A, P);
        caps_partial<<<256, 256, 0, stream>>>(P, P2);
        caps_reduce_squash<<<BATCH * NCAPS, 256, 0, stream>>>(P2, A, out, 16);
    } else {
        int nchunk = 128;
        while (nchunk > 32 &&
               (size_t)(nchunk + 1) * elem * sizeof(float) > ws_size)
            nchunk >>= 1;
        const int rb = NR / nchunk;
        for (int it = 0; it < 3; ++it) {
            caps_route_generic<<<nchunk, 512, 0, stream>>>(x, W, A, P, rb);
            caps_reduce_squash<<<BATCH * NCAPS, 256, 0, stream>>>(
                P, A, it == 2 ? out : nullptr, nchunk);
        }
    }
}